// Round 5
// baseline (585.503 us; speedup 1.0000x reference)
//
#include <hip/hip_runtime.h>

// GNNEncoder_5566277616090: 3-layer GCN + BatchNorm/ReLU + target gather + 2-layer FFN.
// All file-scope symbols uniquely prefixed to avoid any collision with harness-side code.

static const int GNN5566_NN  = 50000;   // nodes
static const int GNN5566_NE  = 800000;  // edges
static const int GNN5566_NB  = 4096;    // batch
static const int GNN5566_CAP = 64;      // max in-degree slots (Poisson(16) tail ~ 1e-18)

static __device__ inline float gnn5566_b2f(unsigned short h){
  return __uint_as_float(((unsigned int)h) << 16);
}
static __device__ inline unsigned short gnn5566_f2b(float f){
  unsigned int u = __float_as_uint(f);
  u += 0x7fffu + ((u >> 16) & 1u);   // round to nearest even
  return (unsigned short)(u >> 16);
}
// load element i from a float buffer that is either fp32 or packed bf16
static __device__ inline float gnn5566_loadf(const void* p, long long i, int isF32){
  if (isF32) return ((const float*)p)[i];
  return gnn5566_b2f(((const unsigned short*)p)[i]);
}

// ---- zero CSR cursors and BN stats ----
__global__ void GNNEncoder_5566277616090_init(int* cur, float* stats){
  int i = blockIdx.x * blockDim.x + threadIdx.x;
  if (i < GNN5566_NN) cur[i] = 0;
  if (i < 512)        stats[i] = 0.0f;
}

// ---- detect input layouts: flags[0]=edge idx int64, flags[1]=target idx int64,
// ---- flags[2]=float inputs are fp32 (else packed bf16) ----
__global__ void GNNEncoder_5566277616090_detect(const int* ei, const int* tgt,
                                                const void* W0, int* flags){
  if (blockIdx.x != 0 || threadIdx.x != 0) return;
  int o1 = 0, o2 = 0;
  for (int i = 0; i < 64; ++i) { o1 |= ei[2*i + 1]; o2 |= tgt[2*i + 1]; }
  flags[0] = (o1 == 0) ? 1 : 0;   // int64: high words of small values are all zero
  flags[1] = (o2 == 0) ? 1 : 0;
  // If W0 is packed bf16, the LOW half of each 32-bit word is a plausible bf16
  // (exponent field near 127). If W0 is fp32, those bits are random mantissa.
  int cnt = 0;
  for (int i = 0; i < 64; ++i) {
    unsigned int w = ((const unsigned int*)W0)[i];
    unsigned int e = (w >> 7) & 255u;
    if (e >= 96u && e <= 134u) cnt++;
  }
  flags[2] = (cnt >= 56) ? 0 : 1;
}

// ---- build padded CSR by destination ----
__global__ void GNNEncoder_5566277616090_fill(const int* ei, int* cur, int* colIdx,
                                              const int* flags){
  int e = blockIdx.x * blockDim.x + threadIdx.x;
  if (e >= GNN5566_NE) return;
  int f = flags[0];
  int s = f ? ei[2*e]                    : ei[e];
  int d = f ? ei[2*(GNN5566_NE + e)]     : ei[GNN5566_NE + e];
  int pos = atomicAdd(&cur[d], 1);
  if (pos < GNN5566_CAP) colIdx[d * GNN5566_CAP + pos] = s;
}

__global__ void GNNEncoder_5566277616090_dinv(const int* cur, float* dinv){
  int i = blockIdx.x * blockDim.x + threadIdx.x;
  if (i < GNN5566_NN) dinv[i] = rsqrtf((float)(cur[i] + 1));   // +1 self loop
}

// ---- GEMM 128 out cols: Out[r][.] = transform(A[row]) . W, K=128 ----
// 16 rows/block, 256 threads. W staged to LDS (bf16); A tile to fp32 LDS with
// optional BN affine+relu, row scale, and row gather applied at stage time.
// A may be external (dtype per flags[2]) or internal bf16 (aExternal=0).
// Out is always internal bf16.
__global__ void GNNEncoder_5566277616090_kernel(const void* A, const void* W,
                                                unsigned short* Out, int nRows,
                                                const float* bnA, const float* bnC,
                                                const float* rowScale,
                                                const int* gather, const int* gatherFlag,
                                                const void* bias, int reluOut,
                                                int aExternal, const int* flags)
{
  __shared__ unsigned short gnnWsh[128 * 128];
  __shared__ float gnnAsh[16 * 128];
  int tid = threadIdx.x;
  int wF32 = flags[2];
  int aF32 = aExternal ? wF32 : 0;

  if (wF32) {
    for (int i = tid; i < 16384; i += 256)
      gnnWsh[i] = gnn5566_f2b(((const float*)W)[i]);
  } else {
    const unsigned int* wg = (const unsigned int*)W;
    unsigned int* wl = (unsigned int*)gnnWsh;
    for (int i = tid; i < 8192; i += 256) wl[i] = wg[i];
  }

  int rowBase = blockIdx.x * 16;
  int row16 = tid >> 4, seg = tid & 15;
  {
    int gr = rowBase + row16;
    int cr = (gr < nRows) ? gr : (nRows - 1);
    int ar = cr;
    if (gather) ar = (*gatherFlag) ? gather[2 * cr] : gather[cr];
    float rs = rowScale ? rowScale[cr] : 1.0f;
    long long base = (long long)ar * 128 + seg * 8;
    for (int j = 0; j < 8; ++j) {
      float v = gnn5566_loadf(A, base + j, aF32);
      if (bnA) { int k = seg * 8 + j; v = fmaxf(v * bnA[k] + bnC[k], 0.0f); }
      gnnAsh[row16 * 128 + seg * 8 + j] = v * rs;
    }
  }
  __syncthreads();

  int c = tid & 127, rsub = tid >> 7;     // rsub in [0,2); this thread does rows rsub+2j
  float acc0 = 0.0f, acc1 = 0.0f, acc2 = 0.0f, acc3 = 0.0f;
  float acc4 = 0.0f, acc5 = 0.0f, acc6 = 0.0f, acc7 = 0.0f;

  for (int k = 0; k < 128; ++k) {
    float wv = gnn5566_b2f(gnnWsh[k * 128 + c]);
    const float* ap = gnnAsh + rsub * 128 + k;
    acc0 += ap[0 * 256] * wv;  acc1 += ap[1 * 256] * wv;
    acc2 += ap[2 * 256] * wv;  acc3 += ap[3 * 256] * wv;
    acc4 += ap[4 * 256] * wv;  acc5 += ap[5 * 256] * wv;
    acc6 += ap[6 * 256] * wv;  acc7 += ap[7 * 256] * wv;
  }

  float badd = bias ? gnn5566_loadf(bias, c, wF32) : 0.0f;
  float accs[8];
  accs[0]=acc0; accs[1]=acc1; accs[2]=acc2; accs[3]=acc3;
  accs[4]=acc4; accs[5]=acc5; accs[6]=acc6; accs[7]=acc7;
  for (int j = 0; j < 8; ++j) {
    int grow = rowBase + rsub + 2 * j;
    if (grow < nRows) {
      float v = accs[j] + badd;
      if (reluOut) v = fmaxf(v, 0.0f);
      Out[(long long)grow * 128 + c] = gnn5566_f2b(v);
    }
  }
}

// ---- GEMM 64 out cols (final FFN layer); writes d_out in the detected dtype ----
__global__ void GNNEncoder_5566277616090_g64(const unsigned short* A, const void* W,
                                             void* Out, int nRows,
                                             const void* bias, const int* flags)
{
  __shared__ unsigned short gnnWsh[128 * 64];
  __shared__ float gnnAsh[16 * 128];
  int tid = threadIdx.x;
  int f32 = flags[2];

  if (f32) {
    for (int i = tid; i < 8192; i += 256)
      gnnWsh[i] = gnn5566_f2b(((const float*)W)[i]);
  } else {
    const unsigned int* wg = (const unsigned int*)W;
    unsigned int* wl = (unsigned int*)gnnWsh;
    for (int i = tid; i < 4096; i += 256) wl[i] = wg[i];
  }

  int rowBase = blockIdx.x * 16;
  int row16 = tid >> 4, seg = tid & 15;
  {
    int gr = rowBase + row16;
    int cr = (gr < nRows) ? gr : (nRows - 1);
    const unsigned short* ap = A + (long long)cr * 128 + seg * 8;
    for (int j = 0; j < 8; ++j)
      gnnAsh[row16 * 128 + seg * 8 + j] = gnn5566_b2f(ap[j]);
  }
  __syncthreads();

  int c = tid & 63, rsub = tid >> 6;      // rsub in [0,4); rows rsub+4j
  float acc0 = 0.0f, acc1 = 0.0f, acc2 = 0.0f, acc3 = 0.0f;
  for (int k = 0; k < 128; ++k) {
    float wv = gnn5566_b2f(gnnWsh[k * 64 + c]);
    const float* ap = gnnAsh + rsub * 128 + k;
    acc0 += ap[0 * 512] * wv;  acc1 += ap[1 * 512] * wv;
    acc2 += ap[2 * 512] * wv;  acc3 += ap[3 * 512] * wv;
  }
  float badd = gnn5566_loadf(bias, c, f32);
  float accs[4];
  accs[0]=acc0; accs[1]=acc1; accs[2]=acc2; accs[3]=acc3;
  for (int j = 0; j < 4; ++j) {
    int grow = rowBase + rsub + 4 * j;
    if (grow < nRows) {
      float v = accs[j] + badd;
      if (f32) ((float*)Out)[(long long)grow * 64 + c] = v;
      else     ((unsigned short*)Out)[(long long)grow * 64 + c] = gnn5566_f2b(v);
    }
  }
}

// ---- aggregation: ha[d] = dinv[d] * (sum_{s in in(d)} hs[s] + hs[d]) + bias ----
// one wave per node; each lane owns 2 features (one 32-bit load per neighbor row)
__global__ void GNNEncoder_5566277616090_agg(const unsigned short* hs, const int* colIdx,
                                             const int* cnt, const float* dinv,
                                             const void* bias, unsigned short* ha,
                                             const int* flags)
{
  int gw = (int)((blockIdx.x * 256u + threadIdx.x) >> 6);
  if (gw >= GNN5566_NN) return;
  int lane = threadIdx.x & 63;
  const unsigned int* hrow = (const unsigned int*)hs;   // 2 bf16 per word
  unsigned int sv = hrow[(long long)gw * 64 + lane];
  float a0 = __uint_as_float(sv << 16);
  float a1 = __uint_as_float(sv & 0xffff0000u);
  int m = cnt[gw]; if (m > GNN5566_CAP) m = GNN5566_CAP;
  const int* cp = colIdx + (long long)gw * GNN5566_CAP;
  int i = 0;
  for (; i + 4 <= m; i += 4) {
    int c0 = cp[i], c1 = cp[i+1], c2 = cp[i+2], c3 = cp[i+3];
    unsigned int v0 = hrow[(long long)c0 * 64 + lane];
    unsigned int v1 = hrow[(long long)c1 * 64 + lane];
    unsigned int v2 = hrow[(long long)c2 * 64 + lane];
    unsigned int v3 = hrow[(long long)c3 * 64 + lane];
    a0 += __uint_as_float(v0 << 16) + __uint_as_float(v1 << 16)
        + __uint_as_float(v2 << 16) + __uint_as_float(v3 << 16);
    a1 += __uint_as_float(v0 & 0xffff0000u) + __uint_as_float(v1 & 0xffff0000u)
        + __uint_as_float(v2 & 0xffff0000u) + __uint_as_float(v3 & 0xffff0000u);
  }
  for (; i < m; ++i) {
    unsigned int v = hrow[(long long)cp[i] * 64 + lane];
    a0 += __uint_as_float(v << 16);
    a1 += __uint_as_float(v & 0xffff0000u);
  }
  float s = dinv[gw];
  int f32 = flags[2];
  float o0 = a0 * s + gnn5566_loadf(bias, lane * 2,     f32);
  float o1 = a1 * s + gnn5566_loadf(bias, lane * 2 + 1, f32);
  unsigned int packed = (unsigned int)gnn5566_f2b(o0)
                      | (((unsigned int)gnn5566_f2b(o1)) << 16);
  ((unsigned int*)ha)[(long long)gw * 64 + lane] = packed;
}

// ---- BN column stats (sum, sum of squares) ----
__global__ void GNNEncoder_5566277616090_stats(const unsigned short* ha, float* stats){
  int c = threadIdx.x & 127, sub = threadIdx.x >> 7;
  float s = 0.0f, s2 = 0.0f;
  for (int r = blockIdx.x * 2 + sub; r < GNN5566_NN; r += 512) {
    float v = gnn5566_b2f(ha[(long long)r * 128 + c]);
    s += v; s2 += v * v;
  }
  atomicAdd(&stats[c], s);
  atomicAdd(&stats[128 + c], s2);
}

__global__ void GNNEncoder_5566277616090_bnfin(const float* stats, const void* g,
                                               const void* bt, float* bnA, float* bnC,
                                               const int* flags){
  int c = threadIdx.x;
  if (c >= 128) return;
  int f32 = flags[2];
  float invN = 1.0f / (float)GNN5566_NN;
  float mu  = stats[c] * invN;
  float var = stats[128 + c] * invN - mu * mu;
  if (var < 0.0f) var = 0.0f;
  float a = gnn5566_loadf(g, c, f32) * rsqrtf(var + 1e-5f);
  bnA[c] = a;
  bnC[c] = gnn5566_loadf(bt, c, f32) - mu * a;
}

extern "C" void kernel_launch(void* const* d_in, const int* in_sizes, int n_in,
                              void* d_out, int out_size, void* d_ws, size_t ws_size,
                              hipStream_t stream)
{
  const void* x   = d_in[0];
  const int*  ei  = (const int*)d_in[1];
  const int*  tgt = (const int*)d_in[2];
  const void* W0  = d_in[3];
  const void* b0  = d_in[4];
  const void* W1  = d_in[5];
  const void* b1  = d_in[6];
  const void* W2  = d_in[7];
  const void* b2  = d_in[8];
  const void* g0  = d_in[9];
  const void* bt0 = d_in[10];
  const void* g1  = d_in[11];
  const void* bt1 = d_in[12];
  const void* f1w = d_in[13];
  const void* f1b = d_in[14];
  const void* f2w = d_in[15];
  const void* fb2 = d_in[16];

  char* ws = (char*)d_ws;
  // static 256B-aligned layout, total < 40 MB
  int*            cur    = (int*)           (ws + 0);
  float*          dinv   = (float*)         (ws + 200192);
  int*            colIdx = (int*)           (ws + 400384);
  unsigned short* hs     = (unsigned short*)(ws + 13200384);
  unsigned short* ha     = (unsigned short*)(ws + 26000384);
  unsigned short* ub     = (unsigned short*)(ws + 38800384);
  float*          stats  = (float*)         (ws + 39848960);
  float*          bn     = (float*)         (ws + 39851008);
  int*            flags  = (int*)           (ws + 39853056);

  float* bn0A = bn;       float* bn0C = bn + 128;
  float* bn1A = bn + 256; float* bn1C = bn + 384;

  GNNEncoder_5566277616090_init  <<<196, 256, 0, stream>>>(cur, stats);
  GNNEncoder_5566277616090_detect<<<1, 64, 0, stream>>>(ei, tgt, W0, flags);
  GNNEncoder_5566277616090_fill  <<<3125, 256, 0, stream>>>(ei, cur, colIdx, flags);
  GNNEncoder_5566277616090_dinv  <<<196, 256, 0, stream>>>(cur, dinv);

  // layer 0: hs = (dinv .* x) @ W0
  GNNEncoder_5566277616090_kernel<<<3125, 256, 0, stream>>>(
      x, W0, hs, GNN5566_NN, (const float*)0, (const float*)0, dinv,
      (const int*)0, (const int*)0, (const void*)0, 0, 1, flags);
  GNNEncoder_5566277616090_agg  <<<12500, 256, 0, stream>>>(hs, colIdx, cur, dinv, b0, ha, flags);
  GNNEncoder_5566277616090_stats<<<256, 256, 0, stream>>>(ha, stats);
  GNNEncoder_5566277616090_bnfin<<<1, 128, 0, stream>>>(stats, g0, bt0, bn0A, bn0C, flags);

  // layer 1: hs = (dinv .* relu(bn0(ha))) @ W1
  GNNEncoder_5566277616090_kernel<<<3125, 256, 0, stream>>>(
      ha, W1, hs, GNN5566_NN, bn0A, bn0C, dinv,
      (const int*)0, (const int*)0, (const void*)0, 0, 0, flags);
  GNNEncoder_5566277616090_agg  <<<12500, 256, 0, stream>>>(hs, colIdx, cur, dinv, b1, ha, flags);
  GNNEncoder_5566277616090_stats<<<256, 256, 0, stream>>>(ha, stats + 256);
  GNNEncoder_5566277616090_bnfin<<<1, 128, 0, stream>>>(stats + 256, g1, bt1, bn1A, bn1C, flags);

  // layer 2: hs = (dinv .* relu(bn1(ha))) @ W2
  GNNEncoder_5566277616090_kernel<<<3125, 256, 0, stream>>>(
      ha, W2, hs, GNN5566_NN, bn1A, bn1C, dinv,
      (const int*)0, (const int*)0, (const void*)0, 0, 0, flags);
  GNNEncoder_5566277616090_agg  <<<12500, 256, 0, stream>>>(hs, colIdx, cur, dinv, b2, ha, flags);

  // FFN: ub = relu(ha[tgt] @ f1w + f1b); out = ub @ f2w + fb2
  GNNEncoder_5566277616090_kernel<<<256, 256, 0, stream>>>(
      ha, f1w, ub, GNN5566_NB, (const float*)0, (const float*)0, (const float*)0,
      tgt, flags + 1, f1b, 1, 0, flags);
  GNNEncoder_5566277616090_g64<<<256, 256, 0, stream>>>(ub, f2w, d_out, GNN5566_NB, fb2, flags);
}

// Round 6
// 438.399 us; speedup vs baseline: 1.3355x; 1.3355x over previous
//
#include <hip/hip_runtime.h>

// GNNEncoder_5566277616090: 3-layer GCN + BatchNorm/ReLU + target gather + 2-layer FFN.
// All file-scope symbols uniquely prefixed (round-5 lesson: short names collide with
// harness-side TU code and silently kill the build).

static const int GNN5566_NN  = 50000;   // nodes
static const int GNN5566_NE  = 800000;  // edges
static const int GNN5566_NB  = 4096;    // batch
static const int GNN5566_CAP = 64;      // max in-degree slots (Poisson(16) tail ~ 1e-18)

typedef short gnn5566_s16x8 __attribute__((ext_vector_type(8)));  // 8 bf16 payloads
typedef float gnn5566_f32x4 __attribute__((ext_vector_type(4)));  // MFMA accumulator

static __device__ inline float gnn5566_b2f(unsigned short h){
  return __uint_as_float(((unsigned int)h) << 16);
}
static __device__ inline unsigned short gnn5566_f2b(float f){
  unsigned int u = __float_as_uint(f);
  u += 0x7fffu + ((u >> 16) & 1u);   // round to nearest even
  return (unsigned short)(u >> 16);
}
// load element i from a float buffer that is either fp32 or packed bf16
static __device__ inline float gnn5566_loadf(const void* p, long long i, int isF32){
  if (isF32) return ((const float*)p)[i];
  return gnn5566_b2f(((const unsigned short*)p)[i]);
}

// ---- zero CSR cursors and BN stats ----
__global__ void GNNEncoder_5566277616090_init(int* cur, float* stats){
  int i = blockIdx.x * blockDim.x + threadIdx.x;
  if (i < GNN5566_NN) cur[i] = 0;
  if (i < 512)        stats[i] = 0.0f;
}

// ---- detect input layouts: flags[0]=edge idx int64, flags[1]=target idx int64,
// ---- flags[2]=float inputs are fp32 (else packed bf16) ----
__global__ void GNNEncoder_5566277616090_detect(const int* ei, const int* tgt,
                                                const void* W0, int* flags){
  if (blockIdx.x != 0 || threadIdx.x != 0) return;
  int o1 = 0, o2 = 0;
  for (int i = 0; i < 64; ++i) { o1 |= ei[2*i + 1]; o2 |= tgt[2*i + 1]; }
  flags[0] = (o1 == 0) ? 1 : 0;   // int64: high words of small values are all zero
  flags[1] = (o2 == 0) ? 1 : 0;
  int cnt = 0;
  for (int i = 0; i < 64; ++i) {
    unsigned int w = ((const unsigned int*)W0)[i];
    unsigned int e = (w >> 7) & 255u;
    if (e >= 96u && e <= 134u) cnt++;    // low half looks like bf16 -> packed bf16
  }
  flags[2] = (cnt >= 56) ? 0 : 1;
}

// ---- build padded CSR by destination ----
__global__ void GNNEncoder_5566277616090_fill(const int* ei, int* cur, int* colIdx,
                                              const int* flags){
  int e = blockIdx.x * blockDim.x + threadIdx.x;
  if (e >= GNN5566_NE) return;
  int f = flags[0];
  int s = f ? ei[2*e]                    : ei[e];
  int d = f ? ei[2*(GNN5566_NE + e)]     : ei[GNN5566_NE + e];
  int pos = atomicAdd(&cur[d], 1);
  if (pos < GNN5566_CAP) colIdx[d * GNN5566_CAP + pos] = s;
}

__global__ void GNNEncoder_5566277616090_dinv(const int* cur, float* dinv){
  int i = blockIdx.x * blockDim.x + threadIdx.x;
  if (i < GNN5566_NN) dinv[i] = rsqrtf((float)(cur[i] + 1));   // +1 self loop
}

// ---- MFMA GEMM, 128 out cols: Out[r][.] = transform(A[row]) . W, K=128 ----
// 64 rows/block (4 waves x 16 rows), 256 threads. W staged TRANSPOSED into LDS
// (lw[c][k], +8 u16 pad). A-row transform: optional BN affine+relu, row scale,
// row gather. Out always internal bf16. mfma_f32_16x16x32_bf16:
//   A-frag a[j] = A[m=lane&15][k=(lane>>4)*8+j], B-frag b[j] = B[k][n=lane&15],
//   C/D: col=lane&15, row=(lane>>4)*4+reg.
__global__ void GNNEncoder_5566277616090_kernel(const void* A, const void* W,
                                                unsigned short* Out, int nRows,
                                                const float* bnA, const float* bnC,
                                                const float* rowScale,
                                                const int* gather, const int* gatherFlag,
                                                const void* bias, int reluOut,
                                                int aExternal, const int* flags)
{
  __shared__ unsigned short gnnLw[128 * 136];
  int tid = threadIdx.x;
  int wF32 = flags[2];
  int aF32 = aExternal ? wF32 : 0;

  // stage W transposed: gnnLw[c*136 + k] = W[k*128 + c], converted to bf16
  if (wF32) {
    const float* wf = (const float*)W;
    for (int i = tid; i < 16384; i += 256) {
      int k = i >> 7, c = i & 127;
      gnnLw[c * 136 + k] = gnn5566_f2b(wf[i]);
    }
  } else {
    const unsigned int* wg = (const unsigned int*)W;
    for (int i = tid; i < 8192; i += 256) {
      unsigned int v = wg[i];
      int k = i >> 6, c2 = (i & 63) * 2;
      gnnLw[c2 * 136 + k]       = (unsigned short)(v & 0xffffu);
      gnnLw[(c2 + 1) * 136 + k] = (unsigned short)(v >> 16);
    }
  }
  __syncthreads();

  int wave = tid >> 6, lane = tid & 63;
  int q = lane >> 4, ln = lane & 15;
  int rowBase = blockIdx.x * 64 + wave * 16;
  int r  = rowBase + ln;
  int cr = (r < nRows) ? r : (nRows - 1);
  int ar = cr;
  if (gather) ar = (*gatherFlag) ? gather[2 * cr] : gather[cr];
  float rs = rowScale ? rowScale[cr] : 1.0f;

  // build the 4 A-fragments (k = kk*32 + q*8 + j), transform applied in fp32
  gnn5566_s16x8 afr[4];
  for (int kk = 0; kk < 4; ++kk) {
    int kb = kk * 32 + q * 8;
    long long base = (long long)ar * 128 + kb;
    #pragma unroll
    for (int j = 0; j < 8; ++j) {
      float v = gnn5566_loadf(A, base + j, aF32);
      if (bnA) { int k = kb + j; v = fmaxf(v * bnA[k] + bnC[k], 0.0f); }
      afr[kk][j] = (short)gnn5566_f2b(v * rs);
    }
  }

  gnn5566_f32x4 zero4;
  zero4[0] = 0.0f; zero4[1] = 0.0f; zero4[2] = 0.0f; zero4[3] = 0.0f;
  gnn5566_f32x4 acc[8];
  #pragma unroll
  for (int t = 0; t < 8; ++t) acc[t] = zero4;

  #pragma unroll
  for (int kk = 0; kk < 4; ++kk) {
    int kb = kk * 32 + q * 8;
    #pragma unroll
    for (int t = 0; t < 8; ++t) {
      gnn5566_s16x8 bfr = *(const gnn5566_s16x8*)(&gnnLw[(t * 16 + ln) * 136 + kb]);
      acc[t] = __builtin_amdgcn_mfma_f32_16x16x32_bf16(afr[kk], bfr, acc[t], 0, 0, 0);
    }
  }

  #pragma unroll
  for (int t = 0; t < 8; ++t) {
    int col = t * 16 + ln;
    float badd = bias ? gnn5566_loadf(bias, col, wF32) : 0.0f;
    #pragma unroll
    for (int rg = 0; rg < 4; ++rg) {
      int grow = rowBase + q * 4 + rg;
      if (grow < nRows) {
        float v = acc[t][rg] + badd;
        if (reluOut) v = fmaxf(v, 0.0f);
        Out[(long long)grow * 128 + col] = gnn5566_f2b(v);
      }
    }
  }
}

// ---- MFMA GEMM, 64 out cols (final FFN layer); writes d_out in detected dtype ----
__global__ void GNNEncoder_5566277616090_g64(const unsigned short* A, const void* W,
                                             void* Out, int nRows,
                                             const void* bias, const int* flags)
{
  __shared__ unsigned short gnnLw[64 * 136];
  int tid = threadIdx.x;
  int f32 = flags[2];

  if (f32) {
    const float* wf = (const float*)W;
    for (int i = tid; i < 8192; i += 256) {
      int k = i >> 6, c = i & 63;
      gnnLw[c * 136 + k] = gnn5566_f2b(wf[i]);
    }
  } else {
    const unsigned int* wg = (const unsigned int*)W;
    for (int i = tid; i < 4096; i += 256) {
      unsigned int v = wg[i];
      int k = i >> 5, c2 = (i & 31) * 2;
      gnnLw[c2 * 136 + k]       = (unsigned short)(v & 0xffffu);
      gnnLw[(c2 + 1) * 136 + k] = (unsigned short)(v >> 16);
    }
  }
  __syncthreads();

  int wave = tid >> 6, lane = tid & 63;
  int q = lane >> 4, ln = lane & 15;
  int rowBase = blockIdx.x * 64 + wave * 16;
  int r  = rowBase + ln;
  int cr = (r < nRows) ? r : (nRows - 1);

  gnn5566_s16x8 afr[4];
  for (int kk = 0; kk < 4; ++kk) {
    int kb = kk * 32 + q * 8;
    const unsigned short* ap = A + (long long)cr * 128 + kb;
    #pragma unroll
    for (int j = 0; j < 8; ++j) afr[kk][j] = (short)ap[j];
  }

  gnn5566_f32x4 zero4;
  zero4[0] = 0.0f; zero4[1] = 0.0f; zero4[2] = 0.0f; zero4[3] = 0.0f;
  gnn5566_f32x4 acc[4];
  #pragma unroll
  for (int t = 0; t < 4; ++t) acc[t] = zero4;

  #pragma unroll
  for (int kk = 0; kk < 4; ++kk) {
    int kb = kk * 32 + q * 8;
    #pragma unroll
    for (int t = 0; t < 4; ++t) {
      gnn5566_s16x8 bfr = *(const gnn5566_s16x8*)(&gnnLw[(t * 16 + ln) * 136 + kb]);
      acc[t] = __builtin_amdgcn_mfma_f32_16x16x32_bf16(afr[kk], bfr, acc[t], 0, 0, 0);
    }
  }

  #pragma unroll
  for (int t = 0; t < 4; ++t) {
    int col = t * 16 + ln;
    float badd = gnn5566_loadf(bias, col, f32);
    #pragma unroll
    for (int rg = 0; rg < 4; ++rg) {
      int grow = rowBase + q * 4 + rg;
      if (grow < nRows) {
        float v = acc[t][rg] + badd;
        if (f32) ((float*)Out)[(long long)grow * 64 + col] = v;
        else     ((unsigned short*)Out)[(long long)grow * 64 + col] = gnn5566_f2b(v);
      }
    }
  }
}

// ---- aggregation: ha[d] = dinv[d] * (sum_{s in in(d)} hs[s] + hs[d]) + bias ----
// one wave per node; each lane owns 2 features; 8-deep unroll for load-level parallelism
__global__ void GNNEncoder_5566277616090_agg(const unsigned short* hs, const int* colIdx,
                                             const int* cnt, const float* dinv,
                                             const void* bias, unsigned short* ha,
                                             const int* flags)
{
  int gw = (int)((blockIdx.x * 256u + threadIdx.x) >> 6);
  if (gw >= GNN5566_NN) return;
  int lane = threadIdx.x & 63;
  const unsigned int* hrow = (const unsigned int*)hs;   // 2 bf16 per word
  unsigned int sv = hrow[(long long)gw * 64 + lane];
  float a0 = __uint_as_float(sv << 16);
  float a1 = __uint_as_float(sv & 0xffff0000u);
  int m = cnt[gw]; if (m > GNN5566_CAP) m = GNN5566_CAP;
  const int* cp = colIdx + (long long)gw * GNN5566_CAP;
  int i = 0;
  for (; i + 8 <= m; i += 8) {
    unsigned int v0 = hrow[(long long)cp[i    ] * 64 + lane];
    unsigned int v1 = hrow[(long long)cp[i + 1] * 64 + lane];
    unsigned int v2 = hrow[(long long)cp[i + 2] * 64 + lane];
    unsigned int v3 = hrow[(long long)cp[i + 3] * 64 + lane];
    unsigned int v4 = hrow[(long long)cp[i + 4] * 64 + lane];
    unsigned int v5 = hrow[(long long)cp[i + 5] * 64 + lane];
    unsigned int v6 = hrow[(long long)cp[i + 6] * 64 + lane];
    unsigned int v7 = hrow[(long long)cp[i + 7] * 64 + lane];
    a0 += __uint_as_float(v0 << 16) + __uint_as_float(v1 << 16)
        + __uint_as_float(v2 << 16) + __uint_as_float(v3 << 16)
        + __uint_as_float(v4 << 16) + __uint_as_float(v5 << 16)
        + __uint_as_float(v6 << 16) + __uint_as_float(v7 << 16);
    a1 += __uint_as_float(v0 & 0xffff0000u) + __uint_as_float(v1 & 0xffff0000u)
        + __uint_as_float(v2 & 0xffff0000u) + __uint_as_float(v3 & 0xffff0000u)
        + __uint_as_float(v4 & 0xffff0000u) + __uint_as_float(v5 & 0xffff0000u)
        + __uint_as_float(v6 & 0xffff0000u) + __uint_as_float(v7 & 0xffff0000u);
  }
  for (; i + 4 <= m; i += 4) {
    unsigned int v0 = hrow[(long long)cp[i    ] * 64 + lane];
    unsigned int v1 = hrow[(long long)cp[i + 1] * 64 + lane];
    unsigned int v2 = hrow[(long long)cp[i + 2] * 64 + lane];
    unsigned int v3 = hrow[(long long)cp[i + 3] * 64 + lane];
    a0 += __uint_as_float(v0 << 16) + __uint_as_float(v1 << 16)
        + __uint_as_float(v2 << 16) + __uint_as_float(v3 << 16);
    a1 += __uint_as_float(v0 & 0xffff0000u) + __uint_as_float(v1 & 0xffff0000u)
        + __uint_as_float(v2 & 0xffff0000u) + __uint_as_float(v3 & 0xffff0000u);
  }
  for (; i < m; ++i) {
    unsigned int v = hrow[(long long)cp[i] * 64 + lane];
    a0 += __uint_as_float(v << 16);
    a1 += __uint_as_float(v & 0xffff0000u);
  }
  float s = dinv[gw];
  int f32 = flags[2];
  float o0 = a0 * s + gnn5566_loadf(bias, lane * 2,     f32);
  float o1 = a1 * s + gnn5566_loadf(bias, lane * 2 + 1, f32);
  unsigned int packed = (unsigned int)gnn5566_f2b(o0)
                      | (((unsigned int)gnn5566_f2b(o1)) << 16);
  ((unsigned int*)ha)[(long long)gw * 64 + lane] = packed;
}

// ---- BN column stats (sum, sum of squares) ----
__global__ void GNNEncoder_5566277616090_stats(const unsigned short* ha, float* stats){
  int c = threadIdx.x & 127, sub = threadIdx.x >> 7;
  float s = 0.0f, s2 = 0.0f;
  for (int r = blockIdx.x * 2 + sub; r < GNN5566_NN; r += 512) {
    float v = gnn5566_b2f(ha[(long long)r * 128 + c]);
    s += v; s2 += v * v;
  }
  atomicAdd(&stats[c], s);
  atomicAdd(&stats[128 + c], s2);
}

__global__ void GNNEncoder_5566277616090_bnfin(const float* stats, const void* g,
                                               const void* bt, float* bnA, float* bnC,
                                               const int* flags){
  int c = threadIdx.x;
  if (c >= 128) return;
  int f32 = flags[2];
  float invN = 1.0f / (float)GNN5566_NN;
  float mu  = stats[c] * invN;
  float var = stats[128 + c] * invN - mu * mu;
  if (var < 0.0f) var = 0.0f;
  float a = gnn5566_loadf(g, c, f32) * rsqrtf(var + 1e-5f);
  bnA[c] = a;
  bnC[c] = gnn5566_loadf(bt, c, f32) - mu * a;
}

extern "C" void kernel_launch(void* const* d_in, const int* in_sizes, int n_in,
                              void* d_out, int out_size, void* d_ws, size_t ws_size,
                              hipStream_t stream)
{
  const void* x   = d_in[0];
  const int*  ei  = (const int*)d_in[1];
  const int*  tgt = (const int*)d_in[2];
  const void* W0  = d_in[3];
  const void* b0  = d_in[4];
  const void* W1  = d_in[5];
  const void* b1  = d_in[6];
  const void* W2  = d_in[7];
  const void* b2  = d_in[8];
  const void* g0  = d_in[9];
  const void* bt0 = d_in[10];
  const void* g1  = d_in[11];
  const void* bt1 = d_in[12];
  const void* f1w = d_in[13];
  const void* f1b = d_in[14];
  const void* f2w = d_in[15];
  const void* fb2 = d_in[16];

  char* ws = (char*)d_ws;
  // static 256B-aligned layout, total < 40 MB (unchanged from passing round 5)
  int*            cur    = (int*)           (ws + 0);
  float*          dinv   = (float*)         (ws + 200192);
  int*            colIdx = (int*)           (ws + 400384);
  unsigned short* hs     = (unsigned short*)(ws + 13200384);
  unsigned short* ha     = (unsigned short*)(ws + 26000384);
  unsigned short* ub     = (unsigned short*)(ws + 38800384);
  float*          stats  = (float*)         (ws + 39848960);
  float*          bn     = (float*)         (ws + 39851008);
  int*            flags  = (int*)           (ws + 39853056);

  float* bn0A = bn;       float* bn0C = bn + 128;
  float* bn1A = bn + 256; float* bn1C = bn + 384;

  GNNEncoder_5566277616090_init  <<<196, 256, 0, stream>>>(cur, stats);
  GNNEncoder_5566277616090_detect<<<1, 64, 0, stream>>>(ei, tgt, W0, flags);
  GNNEncoder_5566277616090_fill  <<<3125, 256, 0, stream>>>(ei, cur, colIdx, flags);
  GNNEncoder_5566277616090_dinv  <<<196, 256, 0, stream>>>(cur, dinv);

  const int gemmGrid = (GNN5566_NN + 63) / 64;   // 782

  // layer 0: hs = (dinv .* x) @ W0
  GNNEncoder_5566277616090_kernel<<<gemmGrid, 256, 0, stream>>>(
      x, W0, hs, GNN5566_NN, (const float*)0, (const float*)0, dinv,
      (const int*)0, (const int*)0, (const void*)0, 0, 1, flags);
  GNNEncoder_5566277616090_agg  <<<12500, 256, 0, stream>>>(hs, colIdx, cur, dinv, b0, ha, flags);
  GNNEncoder_5566277616090_stats<<<256, 256, 0, stream>>>(ha, stats);
  GNNEncoder_5566277616090_bnfin<<<1, 128, 0, stream>>>(stats, g0, bt0, bn0A, bn0C, flags);

  // layer 1: hs = (dinv .* relu(bn0(ha))) @ W1
  GNNEncoder_5566277616090_kernel<<<gemmGrid, 256, 0, stream>>>(
      ha, W1, hs, GNN5566_NN, bn0A, bn0C, dinv,
      (const int*)0, (const int*)0, (const void*)0, 0, 0, flags);
  GNNEncoder_5566277616090_agg  <<<12500, 256, 0, stream>>>(hs, colIdx, cur, dinv, b1, ha, flags);
  GNNEncoder_5566277616090_stats<<<256, 256, 0, stream>>>(ha, stats + 256);
  GNNEncoder_5566277616090_bnfin<<<1, 128, 0, stream>>>(stats + 256, g1, bt1, bn1A, bn1C, flags);

  // layer 2: hs = (dinv .* relu(bn1(ha))) @ W2
  GNNEncoder_5566277616090_kernel<<<gemmGrid, 256, 0, stream>>>(
      ha, W2, hs, GNN5566_NN, bn1A, bn1C, dinv,
      (const int*)0, (const int*)0, (const void*)0, 0, 0, flags);
  GNNEncoder_5566277616090_agg  <<<12500, 256, 0, stream>>>(hs, colIdx, cur, dinv, b2, ha, flags);

  // FFN: ub = relu(ha[tgt] @ f1w + f1b); out = ub @ f2w + fb2
  GNNEncoder_5566277616090_kernel<<<64, 256, 0, stream>>>(
      ha, f1w, ub, GNN5566_NB, (const float*)0, (const float*)0, (const float*)0,
      tgt, flags + 1, f1b, 1, 0, flags);
  GNNEncoder_5566277616090_g64<<<64, 256, 0, stream>>>(ub, f2w, d_out, GNN5566_NB, fb2, flags);
}